// Round 1
// baseline (78.571 us; speedup 1.0000x reference)
//
#include <hip/hip_runtime.h>

// Problem constants (from reference): x shape (64, 256, 56, 56) f32
constexpr int B  = 64;
constexpr int C  = 256;
constexpr int H  = 56;
constexpr int W  = 56;
constexpr int G  = 51;      // C / 5
constexpr int W4 = W / 4;   // 14 float4 per row (224 B, 16B-aligned rows)
constexpr int N4 = B * C * H * W4;  // 12,845,056 float4 outputs

__global__ __launch_bounds__(256) void shift_kernel(const float* __restrict__ in,
                                                    float* __restrict__ out) {
    const int stride = gridDim.x * blockDim.x;
    for (int i = blockIdx.x * blockDim.x + threadIdx.x; i < N4; i += stride) {
        // i -> (row t, w4); t = ((b*C + c)*H + h)
        const int w4 = i % W4;
        const int t  = i / W4;
        const int h  = t % H;
        const int c  = (t / H) % C;

        const int row_base = t * W;          // float index of row start
        const int idx      = row_base + 4 * w4;

        float4 r;
        if (c < G) {
            // group 0: roll +1 along H, row 0 -> 0   (out[h] = in[h-1])
            if (h == 0) {
                r = make_float4(0.f, 0.f, 0.f, 0.f);
            } else {
                r = *reinterpret_cast<const float4*>(in + idx - W);
            }
        } else if (c < 2 * G) {
            // group 1: roll -1 along W, col W-1 -> 0 (out[w] = in[w+1])
            const float4 v = *reinterpret_cast<const float4*>(in + idx);
            const float  s = (w4 == W4 - 1) ? 0.f : in[idx + 4];
            r = make_float4(v.y, v.z, v.w, s);
        } else if (c < 3 * G) {
            // group 2: roll -1 along H, row H-1 -> 0 (out[h] = in[h+1])
            if (h == H - 1) {
                r = make_float4(0.f, 0.f, 0.f, 0.f);
            } else {
                r = *reinterpret_cast<const float4*>(in + idx + W);
            }
        } else if (c < 4 * G) {
            // group 3: roll +1 along W, col 0 -> 0   (out[w] = in[w-1])
            const float4 v = *reinterpret_cast<const float4*>(in + idx);
            const float  s = (w4 == 0) ? 0.f : in[idx - 1];
            r = make_float4(s, v.x, v.y, v.z);
        } else {
            // group 4: identity
            r = *reinterpret_cast<const float4*>(in + idx);
        }
        *reinterpret_cast<float4*>(out + idx) = r;
    }
}

extern "C" void kernel_launch(void* const* d_in, const int* in_sizes, int n_in,
                              void* d_out, int out_size, void* d_ws, size_t ws_size,
                              hipStream_t stream) {
    const float* in  = (const float*)d_in[0];
    float*       out = (float*)d_out;
    dim3 grid(2048), block(256);
    hipLaunchKernelGGL(shift_kernel, grid, block, 0, stream, in, out);
}

// Round 2
// 64.200 us; speedup vs baseline: 1.2238x; 1.2238x over previous
//
#include <hip/hip_runtime.h>

// x shape (64, 256, 56, 56) f32; 5-group spatial shift.
constexpr int B  = 64;
constexpr int C  = 256;
constexpr int H  = 56;
constexpr int W  = 56;
constexpr int G  = 51;            // C / 5
constexpr int W4 = W / 4;         // 14 float4 per row (rows 16B-aligned)
constexpr int N4 = B * C * H * W4;   // 12,845,056 float4 outputs
constexpr int ITEMS = 4;
constexpr int BLOCK = 256;
constexpr int TILE  = BLOCK * ITEMS;   // 1024 float4 per block
constexpr int NBLK  = N4 / TILE;       // 12544 exactly (no remainder)

typedef float f4 __attribute__((ext_vector_type(4)));

__global__ __launch_bounds__(BLOCK) void shift_kernel(const float* __restrict__ in,
                                                      float* __restrict__ out) {
    const int tid  = threadIdx.x;
    const int lane = tid & 63;
    const int i0   = blockIdx.x * TILE + tid;

    int idx[ITEMS];
    int gg[ITEMS];
    int w4a[ITEMS];
    f4  v[ITEMS];

    // Phase 1: index math + unconditional (clamped) loads -> 4 loads in flight.
    #pragma unroll
    for (int k = 0; k < ITEMS; ++k) {
        const int i  = i0 + k * BLOCK;
        const int w4 = i % W4;
        const int t  = i / W4;           // row id = (b*C + c)*H + h
        const int u  = t / H;            // b*C + c
        const int h  = t - u * H;
        const int c  = u & (C - 1);      // C = 256 pow2

        idx[k] = 4 * i;                  // float index of this float4
        w4a[k] = w4;

        // group 0..4, branchless
        const int g = (c >= G) + (c >= 2 * G) + (c >= 3 * G) + (c >= 4 * G);
        gg[k] = g;

        // H-shift source row offset; boundary rows load own row then zero.
        const bool invalid = (g == 0 && h == 0) || (g == 2 && h == H - 1);
        const int  off     = (g == 0) ? -W : (g == 2) ? W : 0;
        const int  src     = invalid ? idx[k] : idx[k] + off;

        f4 x = *reinterpret_cast<const f4*>(in + src);
        if (invalid) x = (f4){0.f, 0.f, 0.f, 0.f};
        v[k] = x;
    }

    // Phase 2: in-wave W-shift combine + store.
    #pragma unroll
    for (int k = 0; k < ITEMS; ++k) {
        const int w4 = w4a[k];
        const int g  = gg[k];
        const f4  x  = v[k];

        // neighbor elements via cross-lane shuffle (lanes hold consecutive i)
        const float nxtx = __shfl_down(x.x, 1, 64);
        const float prvw = __shfl_up(x.w, 1, 64);

        float nxt = (w4 == W4 - 1) ? 0.f : nxtx;   // group 1: in[w+1], last col -> 0
        float prv = (w4 == 0)      ? 0.f : prvw;   // group 3: in[w-1], first col -> 0

        // wave-edge fallback: shuffle can't cross wave boundary (rare lanes only)
        if (g == 1 && lane == 63 && w4 != W4 - 1) nxt = in[idx[k] + 4];
        if (g == 3 && lane == 0  && w4 != 0)      prv = in[idx[k] - 1];

        f4 r;
        if (g == 1)      r = (f4){x.y, x.z, x.w, nxt};
        else if (g == 3) r = (f4){prv, x.x, x.y, x.z};
        else             r = x;   // groups 0/2/4 (already row-shifted / zeroed / copied)

        __builtin_nontemporal_store(r, reinterpret_cast<f4*>(out + idx[k]));
    }
}

extern "C" void kernel_launch(void* const* d_in, const int* in_sizes, int n_in,
                              void* d_out, int out_size, void* d_ws, size_t ws_size,
                              hipStream_t stream) {
    const float* in  = (const float*)d_in[0];
    float*       out = (float*)d_out;
    hipLaunchKernelGGL(shift_kernel, dim3(NBLK), dim3(BLOCK), 0, stream, in, out);
}